// Round 2
// baseline (172.943 us; speedup 1.0000x reference)
//
#include <hip/hip_runtime.h>

// HighOrderActivationA: per (b,g): sort 4 inputs asc with argsort indices,
// coef = [s0, s1-s0, s2-s1, s3-s2], idx[k] = suffix-sum of (1<<ind[j]) for j>=k,
// out[b,g,:] = sum_k coef[k] * params[g, idx[k], :]   (O=16)
//
// B=8192, G=256, arity=4, O=16, fp32.  Memory-bound: 32MB read + 128MB write.
//
// R2 = R1 with the compile fix: __builtin_nontemporal_* requires a native
// clang vector type, not HIP's float4 struct. Use ext_vector_type(4).
//
// R1 changes vs the 176.2us kernel:
//  - TB 16->32: each thread computes TWO b-rows (bb, bb+16). Halves the
//    per-block param staging (was 8192 blocks x 16KB = 128MB of L2->LDS
//    traffic, equal to the entire output write) and halves barriers per
//    output byte. Both X loads issued up-front to overlap HBM latency.
//  - Non-temporal store for out (128MB pure streaming, zero reuse) and
//    non-temporal load for X: keep L2 free for the params, which are the
//    only reused data (256KB, fully L2-resident).

typedef float f32x4 __attribute__((ext_vector_type(4)));

#define TB 32          // b-rows per block (2 per thread)
#define TG 16          // groups per block
#define TSTRIDE 260    // 16 rows * 16 floats + 4 pad (65 float4, odd -> bank spread)

__global__ __launch_bounds__(1024, 2) void hoa_kernel(
    const float* __restrict__ X, const float* __restrict__ P,
    float* __restrict__ out, int B, int G)
{
    __shared__ float lds[TG * TSTRIDE];   // 16.25 KB

    const int tid = threadIdx.x;
    const int g0 = blockIdx.y * TG;
    const int b0 = blockIdx.x * TB;

    // ---- stage TG param tables (16 tables x 64 float4 = 1024 float4) ----
    {
        int table = tid >> 6;                 // 0..15
        int within = tid & 63;                // float4 index within table
        f32x4 v = *reinterpret_cast<const f32x4*>(
            P + (size_t)(g0 + table) * 256 + within * 4);
        *reinterpret_cast<f32x4*>(&lds[table * TSTRIDE + within * 4]) = v;
    }
    __syncthreads();

    const int c  = tid & 3;          // output float4 chunk
    const int gg = (tid >> 2) & 15;  // group within tile
    const int bb = tid >> 6;         // b-row within half-tile (== wave id)
    const int g  = g0 + gg;
    const int b_lo = b0 + bb;        // row 0 for this thread
    const int b_hi = b_lo + 16;      // row 1 for this thread

    const float* tab = &lds[gg * TSTRIDE + c * 4];

    // ---- issue both X loads up front (latency overlap) ----
    f32x4 x_pair[2];
    if (b_lo < B)
        x_pair[0] = __builtin_nontemporal_load(
            reinterpret_cast<const f32x4*>(X + (size_t)b_lo * (G * 4) + g * 4));
    if (b_hi < B)
        x_pair[1] = __builtin_nontemporal_load(
            reinterpret_cast<const f32x4*>(X + (size_t)b_hi * (G * 4) + g * 4));

#pragma unroll
    for (int r = 0; r < 2; ++r) {
        const int b = (r == 0) ? b_lo : b_hi;
        if (b >= B) continue;
        f32x4 x = x_pair[r];
        float v0 = x.x, v1 = x.y, v2 = x.z, v3 = x.w;
        int i0 = 0, i1 = 1, i2 = 2, i3 = 3;

        // ---- branchless 4-element sorting network with index tracking ----
#define CSWAP(va, vb, ia, ib)                         \
        {                                             \
            bool sw_ = (va) > (vb);                   \
            float lo_ = sw_ ? (vb) : (va);            \
            float hi_ = sw_ ? (va) : (vb);            \
            int il_ = sw_ ? (ib) : (ia);              \
            int ih_ = sw_ ? (ia) : (ib);              \
            (va) = lo_; (vb) = hi_; (ia) = il_; (ib) = ih_; \
        }
        CSWAP(v0, v1, i0, i1);
        CSWAP(v2, v3, i2, i3);
        CSWAP(v0, v2, i0, i2);
        CSWAP(v1, v3, i1, i3);
        CSWAP(v1, v2, i1, i2);
#undef CSWAP

        // ---- coefficients & suffix-sum bit indices ----
        float c0 = v0, c1 = v1 - v0, c2 = v2 - v1, c3 = v3 - v2;
        int idx0 = 15;
        int idx1 = 15 ^ (1 << i0);
        int idx2 = idx1 ^ (1 << i1);
        int idx3 = 1 << i3;

        // ---- gather this chunk (float4) of 4 table rows from LDS ----
        f32x4 A  = *reinterpret_cast<const f32x4*>(tab + idx0 * 16);
        f32x4 Bv = *reinterpret_cast<const f32x4*>(tab + idx1 * 16);
        f32x4 C  = *reinterpret_cast<const f32x4*>(tab + idx2 * 16);
        f32x4 D  = *reinterpret_cast<const f32x4*>(tab + idx3 * 16);

        f32x4 o;
        o.x = fmaf(c3, D.x, fmaf(c2, C.x, fmaf(c1, Bv.x, c0 * A.x)));
        o.y = fmaf(c3, D.y, fmaf(c2, C.y, fmaf(c1, Bv.y, c0 * A.y)));
        o.z = fmaf(c3, D.z, fmaf(c2, C.z, fmaf(c1, Bv.z, c0 * A.z)));
        o.w = fmaf(c3, D.w, fmaf(c2, C.w, fmaf(c1, Bv.w, c0 * A.w)));

        // ---- fully coalesced streaming store: lanes (c,gg) consecutive ----
        __builtin_nontemporal_store(
            o, reinterpret_cast<f32x4*>(out + (size_t)b * (G * 16) + g * 16 + c * 4));
    }
}

extern "C" void kernel_launch(void* const* d_in, const int* in_sizes, int n_in,
                              void* d_out, int out_size, void* d_ws, size_t ws_size,
                              hipStream_t stream) {
    const float* X = (const float*)d_in[0];
    const float* P = (const float*)d_in[1];
    float* out = (float*)d_out;

    // params: [G, 16, 16] -> G = size/256 ; X: [B, G*4] -> B = size/(G*4)
    int G = in_sizes[1] / 256;
    int B = in_sizes[0] / (G * 4);

    dim3 grid((B + TB - 1) / TB, G / TG);
    hipLaunchKernelGGL(hoa_kernel, grid, dim3(1024), 0, stream, X, P, out, B, G);
}

// Round 4
// 171.132 us; speedup vs baseline: 1.0106x; 1.0106x over previous
//
#include <hip/hip_runtime.h>

// HighOrderActivationA: per (b,g): sort 4 inputs asc with argsort indices,
// coef = [s0, s1-s0, s2-s1, s3-s2], idx[k] = suffix-sum of (1<<ind[j]) for j>=k,
// out[b,g,:] = sum_k coef[k] * params[g, idx[k], :]   (O=16)
//
// B=8192, G=256, arity=4, O=16, fp32.  Memory-bound: 32MB read + 128MB write,
// roofline ~27us @ 6.3TB/s.
//
// R4 = R3 resubmitted unchanged (R3 bench was an infra failure: container
// failed twice; no counters, no compile error -> no evidence to act on).
//
// R3: persistent-strip restructure. Evidence from R2 rocprof: hoa_kernel is
// absent from the top-5 dispatches (all 512MiB fills @ ~85us), so the kernel
// itself is ~85us and dur_us = fill + kernel. R1's staging halving gained
// only ~3us -> staging bytes were never the cost; the cost is 4096
// short-lived blocks each paying {stage -> full barrier -> 2 rows -> exit}.
//
//  - Each block now owns a (64 b-rows x 16 groups) strip: stage 16 tables
//    ONCE, one barrier, then stream 64 rows with zero further barriers.
//  - 512 threads = 8 waves; wave w handles rows w, w+8, ..., w+56.
//  - All 8 X loads per thread issued up front (32 VGPRs in flight, fully
//    unrolled, static indexing) to overlap HBM latency with sort+gather.
//  - Stores stay fully coalesced 1KB-per-wave nt-stores; X loads nt (zero
//    reuse; intra-wave duplicate addresses are merged by the coalescer).

typedef float f32x4 __attribute__((ext_vector_type(4)));

#define NT 512         // threads per block (8 waves)
#define TG 16          // groups per block
#define ROWS 64        // b-rows per block (8 per wave)
#define RPW 8          // rows per wave
#define TSTRIDE 260    // 16 rows * 16 floats + 4 pad

__global__ __launch_bounds__(NT, 4) void hoa_kernel(
    const float* __restrict__ X, const float* __restrict__ P,
    float* __restrict__ out, int B, int G)
{
    __shared__ float lds[TG * TSTRIDE];   // 16.25 KB

    const int tid = threadIdx.x;
    const int g0 = blockIdx.y * TG;
    const int b0 = blockIdx.x * ROWS;

    // ---- stage TG param tables (1024 float4, 2 per thread), once ----
#pragma unroll
    for (int i = 0; i < 2; ++i) {
        int idx = tid + i * NT;               // 0..1023
        int table = idx >> 6;                 // 0..15
        int within = idx & 63;                // float4 index within table
        f32x4 v = *reinterpret_cast<const f32x4*>(
            P + (size_t)(g0 + table) * 256 + within * 4);
        *reinterpret_cast<f32x4*>(&lds[table * TSTRIDE + within * 4]) = v;
    }
    __syncthreads();

    const int c  = tid & 3;          // output float4 chunk
    const int gg = (tid >> 2) & 15;  // group within tile
    const int wv = tid >> 6;         // wave id 0..7
    const int g  = g0 + gg;

    const float* tab = &lds[gg * TSTRIDE + c * 4];
    const float* xp  = X   + (size_t)(b0 + wv) * (G * 4)  + g * 4;
    float*       op  = out + (size_t)(b0 + wv) * (G * 16) + g * 16 + c * 4;
    const size_t xstride = (size_t)RPW * G * 4;    // 8 rows in X (floats)
    const size_t ostride = (size_t)RPW * G * 16;   // 8 rows in out (floats)

    // ---- issue all 8 row-loads up front: deep MLP, HBM latency overlap ----
    f32x4 xs[RPW];
#pragma unroll
    for (int r = 0; r < RPW; ++r) {
        if (b0 + wv + r * 8 < B)
            xs[r] = __builtin_nontemporal_load(
                reinterpret_cast<const f32x4*>(xp + r * xstride));
    }

#pragma unroll
    for (int r = 0; r < RPW; ++r) {
        if (b0 + wv + r * 8 >= B) continue;
        float v0 = xs[r].x, v1 = xs[r].y, v2 = xs[r].z, v3 = xs[r].w;
        int i0 = 0, i1 = 1, i2 = 2, i3 = 3;

        // ---- branchless 4-element sorting network with index tracking ----
#define CSWAP(va, vb, ia, ib)                         \
        {                                             \
            bool sw_ = (va) > (vb);                   \
            float lo_ = sw_ ? (vb) : (va);            \
            float hi_ = sw_ ? (va) : (vb);            \
            int il_ = sw_ ? (ib) : (ia);              \
            int ih_ = sw_ ? (ia) : (ib);              \
            (va) = lo_; (vb) = hi_; (ia) = il_; (ib) = ih_; \
        }
        CSWAP(v0, v1, i0, i1);
        CSWAP(v2, v3, i2, i3);
        CSWAP(v0, v2, i0, i2);
        CSWAP(v1, v3, i1, i3);
        CSWAP(v1, v2, i1, i2);
#undef CSWAP

        // ---- coefficients & suffix-sum bit indices ----
        float c0 = v0, c1 = v1 - v0, c2 = v2 - v1, c3 = v3 - v2;
        int idx0 = 15;
        int idx1 = 15 ^ (1 << i0);
        int idx2 = idx1 ^ (1 << i1);
        int idx3 = 1 << i3;

        // ---- gather this chunk (float4) of 4 table rows from LDS ----
        f32x4 A  = *reinterpret_cast<const f32x4*>(tab + idx0 * 16);
        f32x4 Bv = *reinterpret_cast<const f32x4*>(tab + idx1 * 16);
        f32x4 C  = *reinterpret_cast<const f32x4*>(tab + idx2 * 16);
        f32x4 D  = *reinterpret_cast<const f32x4*>(tab + idx3 * 16);

        f32x4 o;
        o.x = fmaf(c3, D.x, fmaf(c2, C.x, fmaf(c1, Bv.x, c0 * A.x)));
        o.y = fmaf(c3, D.y, fmaf(c2, C.y, fmaf(c1, Bv.y, c0 * A.y)));
        o.z = fmaf(c3, D.z, fmaf(c2, C.z, fmaf(c1, Bv.z, c0 * A.z)));
        o.w = fmaf(c3, D.w, fmaf(c2, C.w, fmaf(c1, Bv.w, c0 * A.w)));

        // ---- fully coalesced streaming store: wave writes 1KB contiguous ----
        __builtin_nontemporal_store(
            o, reinterpret_cast<f32x4*>(op + r * ostride));
    }
}

extern "C" void kernel_launch(void* const* d_in, const int* in_sizes, int n_in,
                              void* d_out, int out_size, void* d_ws, size_t ws_size,
                              hipStream_t stream) {
    const float* X = (const float*)d_in[0];
    const float* P = (const float*)d_in[1];
    float* out = (float*)d_out;

    // params: [G, 16, 16] -> G = size/256 ; X: [B, G*4] -> B = size/(G*4)
    int G = in_sizes[1] / 256;
    int B = in_sizes[0] / (G * 4);

    dim3 grid((B + ROWS - 1) / ROWS, G / TG);
    hipLaunchKernelGGL(hoa_kernel, grid, dim3(NT), 0, stream, X, P, out, B, G);
}

// Round 5
// 161.225 us; speedup vs baseline: 1.0727x; 1.0614x over previous
//
#include <hip/hip_runtime.h>

// HighOrderActivationA: per (b,g): sort 4 inputs asc with argsort indices,
// coef = [s0, s1-s0, s2-s1, s3-s2], idx[k] = suffix-sum of (1<<ind[j]) for j>=k,
// out[b,g,:] = sum_k coef[k] * params[g, idx[k], :]   (O=16)
//
// B=8192, G=256, arity=4, O=16, fp32.  Memory-bound: 32MB read + 128MB write,
// roofline ~27us @ 6.3TB/s.  Kernel stuck at ~80us (dur_us 171 = 85us harness
// poison-fill + kernel; hoa absent from top-5 so < 83us).
//
// R5 theory: DRAM-page locality, not block structure (R1/R3 nulls killed the
// staging/lifetime theory).  Old grid had b-tile fastest: ~500 co-resident
// blocks shared ONE g-tile and sprayed 1KB stores across the whole 128MB
// output at 16KB stride - every burst opens a new HBM page (fill kernel gets
// 6.3TB/s because it streams sequentially; we got ~2TB/s).
//
//  - Grid flipped: g-tile is now blockIdx.x (fast).  The 16 co-resident
//    blocks of one b-strip cover ALL 256 groups of the same 64 rows; their
//    combined stores tile a contiguous 1MiB output slab -> sequential page
//    bursts after MC merging.  Same for the 256KB X slab.
//  - Waves own 8 CONSECUTIVE rows (wave wv -> b0+wv*8 .. +7): each wave's
//    own store stream ascends at 16KB stride instead of 128KB.
//  - Per-thread work, LDS layout, gather, stores: unchanged from R4.

typedef float f32x4 __attribute__((ext_vector_type(4)));

#define NT 512         // threads per block (8 waves)
#define TG 16          // groups per block
#define ROWS 64        // b-rows per block (8 per wave)
#define RPW 8          // consecutive rows per wave
#define TSTRIDE 260    // 16 rows * 16 floats + 4 pad

__global__ __launch_bounds__(NT, 4) void hoa_kernel(
    const float* __restrict__ X, const float* __restrict__ P,
    float* __restrict__ out, int B, int G)
{
    __shared__ float lds[TG * TSTRIDE];   // 16.25 KB

    const int tid = threadIdx.x;
    const int g0 = blockIdx.x * TG;       // g-tile: FAST block dim (locality)
    const int b0 = blockIdx.y * ROWS;     // b-strip: slow block dim

    // ---- stage TG param tables (1024 float4, 2 per thread), once ----
#pragma unroll
    for (int i = 0; i < 2; ++i) {
        int idx = tid + i * NT;               // 0..1023
        int table = idx >> 6;                 // 0..15
        int within = idx & 63;                // float4 index within table
        f32x4 v = *reinterpret_cast<const f32x4*>(
            P + (size_t)(g0 + table) * 256 + within * 4);
        *reinterpret_cast<f32x4*>(&lds[table * TSTRIDE + within * 4]) = v;
    }
    __syncthreads();

    const int c  = tid & 3;          // output float4 chunk
    const int gg = (tid >> 2) & 15;  // group within tile
    const int wv = tid >> 6;         // wave id 0..7
    const int g  = g0 + gg;
    const int brow = b0 + wv * RPW;  // first of 8 consecutive rows

    const float* tab = &lds[gg * TSTRIDE + c * 4];
    const float* xp  = X   + (size_t)brow * (G * 4)  + g * 4;
    float*       op  = out + (size_t)brow * (G * 16) + g * 16 + c * 4;
    const size_t xstride = (size_t)G * 4;    // 1 row in X (floats)
    const size_t ostride = (size_t)G * 16;   // 1 row in out (floats)

    // ---- issue all 8 row-loads up front: HBM latency overlap ----
    f32x4 xs[RPW];
#pragma unroll
    for (int r = 0; r < RPW; ++r) {
        if (brow + r < B)
            xs[r] = __builtin_nontemporal_load(
                reinterpret_cast<const f32x4*>(xp + r * xstride));
    }

#pragma unroll
    for (int r = 0; r < RPW; ++r) {
        if (brow + r >= B) continue;
        float v0 = xs[r].x, v1 = xs[r].y, v2 = xs[r].z, v3 = xs[r].w;
        int i0 = 0, i1 = 1, i2 = 2, i3 = 3;

        // ---- branchless 4-element sorting network with index tracking ----
#define CSWAP(va, vb, ia, ib)                         \
        {                                             \
            bool sw_ = (va) > (vb);                   \
            float lo_ = sw_ ? (vb) : (va);            \
            float hi_ = sw_ ? (va) : (vb);            \
            int il_ = sw_ ? (ib) : (ia);              \
            int ih_ = sw_ ? (ia) : (ib);              \
            (va) = lo_; (vb) = hi_; (ia) = il_; (ib) = ih_; \
        }
        CSWAP(v0, v1, i0, i1);
        CSWAP(v2, v3, i2, i3);
        CSWAP(v0, v2, i0, i2);
        CSWAP(v1, v3, i1, i3);
        CSWAP(v1, v2, i1, i2);
#undef CSWAP

        // ---- coefficients & suffix-sum bit indices ----
        float c0 = v0, c1 = v1 - v0, c2 = v2 - v1, c3 = v3 - v2;
        int idx0 = 15;
        int idx1 = 15 ^ (1 << i0);
        int idx2 = idx1 ^ (1 << i1);
        int idx3 = 1 << i3;

        // ---- gather this chunk (float4) of 4 table rows from LDS ----
        f32x4 A  = *reinterpret_cast<const f32x4*>(tab + idx0 * 16);
        f32x4 Bv = *reinterpret_cast<const f32x4*>(tab + idx1 * 16);
        f32x4 C  = *reinterpret_cast<const f32x4*>(tab + idx2 * 16);
        f32x4 D  = *reinterpret_cast<const f32x4*>(tab + idx3 * 16);

        f32x4 o;
        o.x = fmaf(c3, D.x, fmaf(c2, C.x, fmaf(c1, Bv.x, c0 * A.x)));
        o.y = fmaf(c3, D.y, fmaf(c2, C.y, fmaf(c1, Bv.y, c0 * A.y)));
        o.z = fmaf(c3, D.z, fmaf(c2, C.z, fmaf(c1, Bv.z, c0 * A.z)));
        o.w = fmaf(c3, D.w, fmaf(c2, C.w, fmaf(c1, Bv.w, c0 * A.w)));

        // ---- coalesced streaming store: wave writes 1KB contiguous,
        //      successive r ascend at 16KB stride (same DRAM page run) ----
        __builtin_nontemporal_store(
            o, reinterpret_cast<f32x4*>(op + r * ostride));
    }
}

extern "C" void kernel_launch(void* const* d_in, const int* in_sizes, int n_in,
                              void* d_out, int out_size, void* d_ws, size_t ws_size,
                              hipStream_t stream) {
    const float* X = (const float*)d_in[0];
    const float* P = (const float*)d_in[1];
    float* out = (float*)d_out;

    // params: [G, 16, 16] -> G = size/256 ; X: [B, G*4] -> B = size/(G*4)
    int G = in_sizes[1] / 256;
    int B = in_sizes[0] / (G * 4);

    dim3 grid(G / TG, (B + ROWS - 1) / ROWS);   // x = g-tile (fast), y = b-strip
    hipLaunchKernelGGL(hoa_kernel, grid, dim3(NT), 0, stream, X, P, out, B, G);
}

// Round 6
// 157.730 us; speedup vs baseline: 1.0965x; 1.0222x over previous
//
#include <hip/hip_runtime.h>

// HighOrderActivationA: per (b,g): sort 4 inputs asc with argsort indices,
// coef = [s0, s1-s0, s2-s1, s3-s2], idx[k] = suffix-sum of (1<<ind[j]) for j>=k,
// out[b,g,:] = sum_k coef[k] * params[g, idx[k], :]   (O=16)
//
// B=8192, G=256, arity=4, O=16, fp32.  Memory-bound: 32MB read + 128MB write,
// roofline ~27us @ 6.3TB/s.  Kernel ~76us (dur 161 = ~85us harness fill +
// kernel; hoa absent from top-5 so < 83us).
//
// R6: single-variable A/B vs R5 -- REMOVE all __builtin_nontemporal_* hints.
// Theory: nt stores bypass L2 write-combining on gfx950 and throttle the
// streaming write path (84% of roofline traffic).  The harness's own fill
// kernel hits 78-80% of peak WITHOUT nt.  nt was introduced in R2 bundled
// with the TB change and never isolated; every structural theory since
// (staging bytes R1, block lifetime R3, DRAM ordering R5) moved <= 10us,
// while VALU(~6us) + LDS(~15us) + HBM(~25us) models leave ~45us unexplained.
// Prediction: if nt throttles, dur -> ~125-140; if 161+-3, theory dead and
// next probe is temporal store clustering.
//
// Structure (unchanged from R5):
//  - g-tile fast block dim: co-resident blocks tile contiguous 1MiB out slabs.
//  - 64-row strip/block, stage 16 tables once, 1 barrier, stream 8 rows/wave.
//  - Waves own 8 consecutive rows; wave store stream ascends at 16KB stride.
//  - All 8 X loads issued up front; 1KB contiguous wave stores.

typedef float f32x4 __attribute__((ext_vector_type(4)));

#define NT 512         // threads per block (8 waves)
#define TG 16          // groups per block
#define ROWS 64        // b-rows per block (8 per wave)
#define RPW 8          // consecutive rows per wave
#define TSTRIDE 260    // 16 rows * 16 floats + 4 pad

__global__ __launch_bounds__(NT, 4) void hoa_kernel(
    const float* __restrict__ X, const float* __restrict__ P,
    float* __restrict__ out, int B, int G)
{
    __shared__ float lds[TG * TSTRIDE];   // 16.25 KB

    const int tid = threadIdx.x;
    const int g0 = blockIdx.x * TG;       // g-tile: FAST block dim (locality)
    const int b0 = blockIdx.y * ROWS;     // b-strip: slow block dim

    // ---- stage TG param tables (1024 float4, 2 per thread), once ----
#pragma unroll
    for (int i = 0; i < 2; ++i) {
        int idx = tid + i * NT;               // 0..1023
        int table = idx >> 6;                 // 0..15
        int within = idx & 63;                // float4 index within table
        f32x4 v = *reinterpret_cast<const f32x4*>(
            P + (size_t)(g0 + table) * 256 + within * 4);
        *reinterpret_cast<f32x4*>(&lds[table * TSTRIDE + within * 4]) = v;
    }
    __syncthreads();

    const int c  = tid & 3;          // output float4 chunk
    const int gg = (tid >> 2) & 15;  // group within tile
    const int wv = tid >> 6;         // wave id 0..7
    const int g  = g0 + gg;
    const int brow = b0 + wv * RPW;  // first of 8 consecutive rows

    const float* tab = &lds[gg * TSTRIDE + c * 4];
    const float* xp  = X   + (size_t)brow * (G * 4)  + g * 4;
    float*       op  = out + (size_t)brow * (G * 16) + g * 16 + c * 4;
    const size_t xstride = (size_t)G * 4;    // 1 row in X (floats)
    const size_t ostride = (size_t)G * 16;   // 1 row in out (floats)

    // ---- issue all 8 row-loads up front: HBM latency overlap ----
    f32x4 xs[RPW];
#pragma unroll
    for (int r = 0; r < RPW; ++r) {
        if (brow + r < B)
            xs[r] = *reinterpret_cast<const f32x4*>(xp + r * xstride);
    }

#pragma unroll
    for (int r = 0; r < RPW; ++r) {
        if (brow + r >= B) continue;
        float v0 = xs[r].x, v1 = xs[r].y, v2 = xs[r].z, v3 = xs[r].w;
        int i0 = 0, i1 = 1, i2 = 2, i3 = 3;

        // ---- branchless 4-element sorting network with index tracking ----
#define CSWAP(va, vb, ia, ib)                         \
        {                                             \
            bool sw_ = (va) > (vb);                   \
            float lo_ = sw_ ? (vb) : (va);            \
            float hi_ = sw_ ? (va) : (vb);            \
            int il_ = sw_ ? (ib) : (ia);              \
            int ih_ = sw_ ? (ia) : (ib);              \
            (va) = lo_; (vb) = hi_; (ia) = il_; (ib) = ih_; \
        }
        CSWAP(v0, v1, i0, i1);
        CSWAP(v2, v3, i2, i3);
        CSWAP(v0, v2, i0, i2);
        CSWAP(v1, v3, i1, i3);
        CSWAP(v1, v2, i1, i2);
#undef CSWAP

        // ---- coefficients & suffix-sum bit indices ----
        float c0 = v0, c1 = v1 - v0, c2 = v2 - v1, c3 = v3 - v2;
        int idx0 = 15;
        int idx1 = 15 ^ (1 << i0);
        int idx2 = idx1 ^ (1 << i1);
        int idx3 = 1 << i3;

        // ---- gather this chunk (float4) of 4 table rows from LDS ----
        f32x4 A  = *reinterpret_cast<const f32x4*>(tab + idx0 * 16);
        f32x4 Bv = *reinterpret_cast<const f32x4*>(tab + idx1 * 16);
        f32x4 C  = *reinterpret_cast<const f32x4*>(tab + idx2 * 16);
        f32x4 D  = *reinterpret_cast<const f32x4*>(tab + idx3 * 16);

        f32x4 o;
        o.x = fmaf(c3, D.x, fmaf(c2, C.x, fmaf(c1, Bv.x, c0 * A.x)));
        o.y = fmaf(c3, D.y, fmaf(c2, C.y, fmaf(c1, Bv.y, c0 * A.y)));
        o.z = fmaf(c3, D.z, fmaf(c2, C.z, fmaf(c1, Bv.z, c0 * A.z)));
        o.w = fmaf(c3, D.w, fmaf(c2, C.w, fmaf(c1, Bv.w, c0 * A.w)));

        // ---- coalesced store (plain, L2 write-back): wave writes 1KB
        //      contiguous, successive r ascend at 16KB stride ----
        *reinterpret_cast<f32x4*>(op + r * ostride) = o;
    }
}

extern "C" void kernel_launch(void* const* d_in, const int* in_sizes, int n_in,
                              void* d_out, int out_size, void* d_ws, size_t ws_size,
                              hipStream_t stream) {
    const float* X = (const float*)d_in[0];
    const float* P = (const float*)d_in[1];
    float* out = (float*)d_out;

    // params: [G, 16, 16] -> G = size/256 ; X: [B, G*4] -> B = size/(G*4)
    int G = in_sizes[1] / 256;
    int B = in_sizes[0] / (G * 4);

    dim3 grid(G / TG, (B + ROWS - 1) / ROWS);   // x = g-tile (fast), y = b-strip
    hipLaunchKernelGGL(hoa_kernel, grid, dim3(NT), 0, stream, X, P, out, B, G);
}